// Round 4
// baseline (315.944 us; speedup 1.0000x reference)
//
#include <hip/hip_runtime.h>
#include <math.h>

typedef __attribute__((ext_vector_type(8))) short bf16x8;
typedef __attribute__((ext_vector_type(4))) float f32x4;

__device__ __forceinline__ unsigned short f2bf(float f) {
    unsigned u = __float_as_uint(f);
    unsigned r = (u + 0x7FFF + ((u >> 16) & 1)) >> 16;   // RNE; inputs finite
    return (unsigned short)r;
}

__device__ __forceinline__ float bf2f(unsigned short s) {
    return __uint_as_float(((unsigned)s) << 16);
}

// fast tanh: 1 - 2/(e^{2x}+1) via v_exp_f32 + v_rcp_f32 (validated R5/R6).
__device__ __forceinline__ float fast_tanh(float x) {
    float e2 = __builtin_amdgcn_exp2f(x * 2.885390081777927f);  // 2*log2(e)
    return fmaf(-2.0f, __builtin_amdgcn_rcpf(e2 + 1.0f), 1.0f);
}

// async global->LDS, 16B per lane; LDS dest = wave-uniform base + lane*16.
__device__ __forceinline__ void gload_lds16(const unsigned short* g,
                                            unsigned short* l) {
    __builtin_amdgcn_global_load_lds(
        (const __attribute__((address_space(1))) unsigned int*)g,
        (__attribute__((address_space(3))) unsigned int*)l, 16, 0, 0);
}

// ---------------------------------------------------------------------------
// castT_tile: one 64(n) x 128(c) tile of fp32 (B,L,128) -> bf16 (B,128,L).
// ---------------------------------------------------------------------------
__device__ __forceinline__ void castT_tile(
    const float* __restrict__ src, unsigned short* __restrict__ dst,
    int b, int n0, int L)
{
    __shared__ unsigned short tt[128][72];
    const int tid = threadIdx.x;
    for (int i = tid; i < 64 * 32; i += 256) {
        int nr = i >> 5, c4 = (i & 31) * 4;
        float4 v = *(const float4*)(src + ((size_t)b * L + n0 + nr) * 128 + c4);
        tt[c4 + 0][nr] = f2bf(v.x);
        tt[c4 + 1][nr] = f2bf(v.y);
        tt[c4 + 2][nr] = f2bf(v.z);
        tt[c4 + 3][nr] = f2bf(v.w);
    }
    __syncthreads();
    const int c = tid >> 1, seg = (tid & 1) * 32;
    unsigned short* dp = dst + ((size_t)b * 128 + c) * L + n0 + seg;
    #pragma unroll
    for (int j = 0; j < 32; j += 8)
        *(bf16x8*)(dp + j) = *(const bf16x8*)&tt[c][seg + j];
}

// ---------------------------------------------------------------------------
// prep_all: ONE dispatch for all independent prep work (unchanged from R6).
// ---------------------------------------------------------------------------
__global__ __launch_bounds__(256) void prep_all(
    const float* __restrict__ x1, const float* __restrict__ x2,
    const float* __restrict__ x3,
    unsigned short* __restrict__ Xt1, unsigned short* __restrict__ Xt2,
    unsigned short* __restrict__ Xt3,
    unsigned short* __restrict__ U256, unsigned short* __restrict__ U128,
    unsigned short* __restrict__ U64p,
    const float* __restrict__ c0, const float* __restrict__ c1,
    const float* __restrict__ c2, const float* __restrict__ c3,
    unsigned short* __restrict__ BmT_all, float* __restrict__ bias_all)
{
    const int bid = blockIdx.x, tid = threadIdx.x;
    if (bid < 896) {
        if (bid < 512)      castT_tile(x1, Xt1, bid >> 2, (bid & 3) * 64, 256);
        else if (bid < 768) castT_tile(x2, Xt2, (bid - 512) >> 1, ((bid - 512) & 1) * 64, 128);
        else                castT_tile(x3, Xt3, bid - 768, 0, 64);
    } else if (bid < 1568) {
        int fid = (bid - 896) * 256 + tid;
        unsigned short* U; int L, lg, e;
        if (fid < 131072)      { U = U256; L = 256; lg = 8; e = fid; }
        else if (fid < 163840) { U = U128; L = 128; lg = 7; e = fid - 131072; }
        else                   { U = U64p; L = 64;  lg = 6; e = fid - 163840; }
        const int n = e & (L - 1);
        const int m = e >> lg;
        const int t = m >> 1;
        const float inv4L = 1.0f / (4.0f * (float)L);
        float val;
        if ((m & 1) == 0) {
            val = ((t == n) ? 0.25f : 0.0f) + (((t + n) & 1) ? -inv4L : inv4L);
        } else {
            int idx = (t - n) & (L - 1);
            double th = M_PI * (2.0 * idx + 1.0) / (2.0 * L);
            double ct = cos(th) / sin(th);
            val = (float)((idx & 1) ? -ct : ct) * inv4L;
        }
        U[e] = f2bf(val);
    } else {
        const int r   = bid - 1568;          // 0..255
        const int set = r >> 6;              // 0..3  (DEG1 = set+2)
        const int o   = ((r & 63) << 1) + (tid >> 7);
        const int i   = tid & 127;
        const int DEG1 = set + 2;
        const float* cc = (set == 0) ? c0 : (set == 1) ? c1 : (set == 2) ? c2 : c3;
        const float* cp = cc + ((size_t)i * 128 + o) * DEG1;
        unsigned short* Bm = BmT_all + (size_t)set * 65536;
        for (int d = 1; d < DEG1; ++d)
            Bm[(size_t)(d - 1) * 16384 + o * 128 + i] = f2bf(cp[d]);
        float s = cp[0];
        #pragma unroll
        for (int off = 32; off >= 1; off >>= 1) s += __shfl_down(s, off);
        __shared__ float red[4];
        if ((tid & 63) == 0) red[tid >> 6] = s;
        __syncthreads();
        if ((tid & 127) == 0)
            bias_all[set * 128 + o] = red[tid >> 6] + red[(tid >> 6) + 1];
    }
}

// ---------------------------------------------------------------------------
// compose1/2: composite upsample matrices (exact: rfft-zero-pad interp
// composes — up(128->256) o up(64->128) == up(64->256)).
// Wcat2 [256][192] = [U128 | U128*U64p]
// Wcat3 [512][448] = [U256 | U256*U128 | U256*U128*U64p]
// fp32 dot products of bf16 entries, rounded once to bf16.
// NOTE: Wcat2/Wcat3 alias the (dead-after-up2_dec) Xt3 region, so these
// run AFTER up2_dec — keeps total ws footprint identical to R6's proven one.
// ---------------------------------------------------------------------------
__global__ __launch_bounds__(256) void compose1(
    const unsigned short* __restrict__ U64p, const unsigned short* __restrict__ U128,
    const unsigned short* __restrict__ U256,
    unsigned short* __restrict__ Wcat2, unsigned short* __restrict__ Wcat3)
{
    int t = blockIdx.x * 256 + threadIdx.x;
    if (t < 32768) {                       // copy U128 -> Wcat2[:,0:128]
        int m = t >> 7, c = t & 127;
        Wcat2[m * 192 + c] = U128[t];
    } else if (t < 49152) {                // W20 -> Wcat2[:,128:192]
        int e = t - 32768, m = e >> 6, q = e & 63;
        float s = 0.f;
        for (int n = 0; n < 128; ++n)
            s += bf2f(U128[m * 128 + n]) * bf2f(U64p[n * 64 + q]);
        Wcat2[m * 192 + 128 + q] = f2bf(s);
    } else if (t < 180224) {               // copy U256 -> Wcat3[:,0:256]
        int e = t - 49152, m = e >> 8, c = e & 255;
        Wcat3[m * 448 + c] = U256[e];
    } else if (t < 245760) {               // W31 -> Wcat3[:,256:384]
        int e = t - 180224, m = e >> 7, q = e & 127;
        float s = 0.f;
        for (int n = 0; n < 256; ++n)
            s += bf2f(U256[m * 256 + n]) * bf2f(U128[n * 128 + q]);
        Wcat3[m * 448 + 256 + q] = f2bf(s);
    }
}

__global__ __launch_bounds__(256) void compose2(
    const unsigned short* __restrict__ U64p, unsigned short* __restrict__ Wcat3)
{
    int t = blockIdx.x * 256 + threadIdx.x;   // 32768: W30 -> Wcat3[:,384:448]
    int m = t >> 6, q = t & 63;
    float s = 0.f;
    for (int n = 0; n < 128; ++n)
        s += bf2f(Wcat3[m * 448 + 256 + n]) * bf2f(U64p[n * 64 + q]);
    Wcat3[m * 448 + 384 + q] = f2bf(s);
}

// ---------------------------------------------------------------------------
// up2_body: out[b,row,c] = xh[b,row,c] + sign * sum_k A[row,k]*B[b,c,k]
// 64x128 tile, 4 waves 2x2 of 32x64, mfma 16x16x32 bf16 (R4-proven skeleton,
// gload_lds staging). Generalized strides: serves up2_dec (A=U, B=Xt) and
// mix_fused (A=Wcat, B=Ktall suffix).
// ---------------------------------------------------------------------------
__device__ __forceinline__ void up2_body(
    const unsigned short* __restrict__ A, int Ars,
    const unsigned short* __restrict__ Bbase, int Brs, int bOff,
    const float* __restrict__ xh, float* __restrict__ out,
    float sign, int b, int mt, int K, int Mrows)
{
    const int NK = K >> 5;
    const int tid = threadIdx.x;
    __shared__ unsigned short Ab[2][2048];
    __shared__ unsigned short Bb[2][4096];

    const int ln = tid & 63, wv = tid >> 6;
    const int wm = wv & 1, wn = wv >> 1;
    const int lr = ln & 15, qd = ln >> 4;

    f32x4 acc[2][4];
    #pragma unroll
    for (int mi = 0; mi < 2; ++mi)
        #pragma unroll
        for (int nt = 0; nt < 4; ++nt)
            acc[mi][nt] = (f32x4){0.f, 0.f, 0.f, 0.f};

    const int arow = tid >> 2, acol = (tid & 3) * 8;

    auto stage = [&](int kk, int buf) {
        const unsigned short* ga = A + (size_t)(mt * 64 + arow) * Ars + kk * 32 + acol;
        gload_lds16(ga, (unsigned short*)Ab[buf] + (tid << 3));
        #pragma unroll
        for (int j = 0; j < 2; ++j) {
            int sidx = tid + (j << 8);
            const unsigned short* gb =
                Bbase + ((size_t)b * 128 + (sidx >> 2)) * Brs + bOff + kk * 32 + (sidx & 3) * 8;
            gload_lds16(gb, (unsigned short*)Bb[buf] + (sidx << 3));
        }
    };

    stage(0, 0);
    for (int kk = 0; kk < NK; ++kk) {
        __syncthreads();                     // drains async loads for buf kk
        if (kk + 1 < NK) stage(kk + 1, (kk + 1) & 1);
        const int buf = kk & 1;
        bf16x8 af[2], bfv[4];
        #pragma unroll
        for (int mi = 0; mi < 2; ++mi)
            af[mi] = *(const bf16x8*)&Ab[buf][(wm * 32 + mi * 16 + lr) * 32 + qd * 8];
        #pragma unroll
        for (int nt = 0; nt < 4; ++nt)
            bfv[nt] = *(const bf16x8*)&Bb[buf][(wn * 64 + nt * 16 + lr) * 32 + qd * 8];
        #pragma unroll
        for (int mi = 0; mi < 2; ++mi)
            #pragma unroll
            for (int nt = 0; nt < 4; ++nt)
                acc[mi][nt] = __builtin_amdgcn_mfma_f32_16x16x32_bf16(
                    af[mi], bfv[nt], acc[mi][nt], 0, 0, 0);
    }

    #pragma unroll
    for (int nt = 0; nt < 4; ++nt) {
        const int col = wn * 64 + nt * 16 + lr;
        #pragma unroll
        for (int mi = 0; mi < 2; ++mi) {
            #pragma unroll
            for (int r = 0; r < 4; ++r) {
                const int row = mt * 64 + wm * 32 + mi * 16 + qd * 4 + r;
                const size_t gi = ((size_t)b * Mrows + row) * 128 + col;
                out[gi] = xh[gi] + sign * acc[mi][nt][r];
            }
        }
    }
}

// up2_dec: all three decomposition GEMMs in ONE dispatch.
__global__ __launch_bounds__(256) void up2_dec(
    const unsigned short* __restrict__ U64p, const unsigned short* __restrict__ U128,
    const unsigned short* __restrict__ U256,
    const unsigned short* __restrict__ Xt3, const unsigned short* __restrict__ Xt2,
    const unsigned short* __restrict__ Xt1,
    const float* __restrict__ x2, const float* __restrict__ x1,
    const float* __restrict__ x0,
    float* __restrict__ d2, float* __restrict__ d1, float* __restrict__ d0)
{
    const int bid = blockIdx.x;
    const unsigned short *U, *Xt; const float* xh; float* out;
    int L, lgMT, base;
    if (bid < 256)      { U = U64p; Xt = Xt3; xh = x2; out = d2; L = 64;  lgMT = 1; base = 0; }
    else if (bid < 768) { U = U128; Xt = Xt2; xh = x1; out = d1; L = 128; lgMT = 2; base = 256; }
    else                { U = U256; Xt = Xt1; xh = x0; out = d0; L = 256; lgMT = 3; base = 768; }
    const int rb = bid - base;
    up2_body(U, L, Xt, L, 0, xh, out, -1.f,
             rb >> lgMT, rb & ((1 << lgMT) - 1), L, L << 1);
}

// mix_fused: ALL THREE mix up-adds in ONE dispatch (independent GEMMs):
//   m1 += U64p  * Kt0          (K=64)
//   m2 += Wcat2 * [Kt1|Kt0]    (K=192)
//   m3 += Wcat3 * [Kt2|Kt1|Kt0](K=448)
__global__ __launch_bounds__(256) void mix_fused(
    const unsigned short* __restrict__ U64p,
    const unsigned short* __restrict__ Wcat2, const unsigned short* __restrict__ Wcat3,
    const unsigned short* __restrict__ Ktall,
    float* __restrict__ m1, float* __restrict__ m2, float* __restrict__ m3)
{
    const int bid = blockIdx.x;
    const unsigned short* A; float* mo;
    int Ars, bOff, K, Mrows, b, mt;
    if (bid < 256)      { A = U64p;  Ars = 64;  bOff = 384; K = 64;  Mrows = 128; mo = m1; b = bid >> 1;          mt = bid & 1; }
    else if (bid < 768) { A = Wcat2; Ars = 192; bOff = 256; K = 192; Mrows = 256; mo = m2; b = (bid - 256) >> 2;  mt = (bid - 256) & 3; }
    else                { A = Wcat3; Ars = 448; bOff = 0;   K = 448; Mrows = 512; mo = m3; b = (bid - 768) >> 3;  mt = (bid - 768) & 7; }
    up2_body(A, Ars, Ktall, 448, bOff, mo, mo, 1.f, b, mt, K, Mrows);
}

// ---------------------------------------------------------------------------
// mkan_all: ALL FOUR mkan levels in one dispatch.
// LDS holds only u = tanh(tanh(x)) in fp32 (16.9KB padded); Chebyshev planes
// generated IN REGISTERS inside a reordered K-loop (col-chunk outer, plane
// inner — accumulation order is free), A-fragments packed with
// v_cvt_pk_bf16_f32 (RNE == f2bf). LDS 48->33.3KB. Epilogue emits transposed
// bf16 K0/K1/K2 into Ktall[b][c][448] ([384:448]=Kt0 [256:384]=Kt1 [0:256]=Kt2).
// ---------------------------------------------------------------------------
__global__ __launch_bounds__(256) void mkan_all(
    const float* __restrict__ xa, const float* __restrict__ xb,
    const float* __restrict__ xc, const float* __restrict__ xd,
    const unsigned short* __restrict__ BmT_all,
    const float* __restrict__ bias_all,
    const float* __restrict__ w0p, const float* __restrict__ w1p,
    const float* __restrict__ w2p, const float* __restrict__ w3p,
    float* __restrict__ m0, float* __restrict__ m1,
    float* __restrict__ m2, float* __restrict__ m3,
    unsigned short* __restrict__ Ktall)
{
    __shared__ float Us[32][132];            // +4 pad: bank-spread, 16B-aligned
    __shared__ unsigned short Bb[2][4096];

    const int bid = blockIdx.x, tid = threadIdx.x;
    const float *x, *w; float* outp; unsigned short* kt = nullptr;
    int set, mb, Lmask, lgL = 9;
    if (bid < 256)       { x = xa; w = w0p; outp = m0; set = 0; mb = bid << 5;          Lmask = 63;  lgL = 6; kt = Ktall + 384; }
    else if (bid < 768)  { x = xb; w = w1p; outp = m1; set = 1; mb = (bid - 256) << 5;  Lmask = 127; lgL = 7; kt = Ktall + 256; }
    else if (bid < 1792) { x = xc; w = w2p; outp = m2; set = 2; mb = (bid - 768) << 5;  Lmask = 255; lgL = 8; kt = Ktall; }
    else                 { x = xd; w = w3p; outp = m3; set = 3; mb = (bid - 1792) << 5; Lmask = 511; }
    const int deg1m1 = set + 1;
    const int NK = deg1m1 << 2;
    const unsigned short* Bm = BmT_all + (size_t)set * 65536;
    const float* bias = bias_all + (set << 7);

    auto stageB = [&](int p, int c4, int buf) {
        const int i0 = c4 << 5;
        #pragma unroll
        for (int j = 0; j < 2; ++j) {
            int sidx = tid + (j << 8);
            const unsigned short* gb =
                Bm + (size_t)((p << 7) + (sidx >> 2)) * 128 + i0 + ((sidx & 3) << 3);
            gload_lds16(gb, (unsigned short*)Bb[buf] + (sidx << 3));
        }
    };

    stageB(0, 0, 0);                         // flies during tanh prep

    // ---- prep: u = tanh(tanh(x)) fp32 into Us ----
    for (int e = tid * 4; e < 4096; e += 1024) {
        const int row = e >> 7, i = e & 127;
        float4 v = *(const float4*)(x + ((size_t)(mb + row)) * 128 + i);
        float4 r;
        r.x = fast_tanh(fast_tanh(v.x));
        r.y = fast_tanh(fast_tanh(v.y));
        r.z = fast_tanh(fast_tanh(v.z));
        r.w = fast_tanh(fast_tanh(v.w));
        *(float4*)&Us[row][i] = r;
    }

    const int ln = tid & 63, wv = tid >> 6;
    const int wm = wv & 1, wn = wv >> 1;
    const int lr = ln & 15, qd = ln >> 4;
    const int arow = (wm << 4) + lr;

    f32x4 acc[4];
    #pragma unroll
    for (int nt = 0; nt < 4; ++nt) acc[nt] = (f32x4){0.f, 0.f, 0.f, 0.f};

    __syncthreads();                         // Us ready + stage(0) drained

    int s = 0;
    for (int c4 = 0; c4 < 4; ++c4) {
        const float4 ua = *(const float4*)&Us[arow][(c4 << 5) + (qd << 3)];
        const float4 ub = *(const float4*)&Us[arow][(c4 << 5) + (qd << 3) + 4];
        const float u0 = ua.x, u1 = ua.y, u2 = ua.z, u3 = ua.w;
        const float u4 = ub.x, u5 = ub.y, u6 = ub.z, u7 = ub.w;
        float tp0 = 1.f, tp1 = 1.f, tp2 = 1.f, tp3 = 1.f;
        float tp4 = 1.f, tp5 = 1.f, tp6 = 1.f, tp7 = 1.f;
        float tc0 = u0, tc1 = u1, tc2 = u2, tc3 = u3;
        float tc4 = u4, tc5 = u5, tc6 = u6, tc7 = u7;
        for (int p = 0; p < deg1m1; ++p, ++s) {
            if (s) __syncthreads();
            if (s + 1 < NK) {
                int np = p + 1, nc4 = c4;
                if (np == deg1m1) { np = 0; ++nc4; }
                stageB(np, nc4, (s + 1) & 1);
            }
            union { unsigned int w[4]; bf16x8 v; } afu;
            asm("v_cvt_pk_bf16_f32 %0, %1, %2" : "=v"(afu.w[0]) : "v"(tc0), "v"(tc1));
            asm("v_cvt_pk_bf16_f32 %0, %1, %2" : "=v"(afu.w[1]) : "v"(tc2), "v"(tc3));
            asm("v_cvt_pk_bf16_f32 %0, %1, %2" : "=v"(afu.w[2]) : "v"(tc4), "v"(tc5));
            asm("v_cvt_pk_bf16_f32 %0, %1, %2" : "=v"(afu.w[3]) : "v"(tc6), "v"(tc7));
            const int buf = s & 1;
            bf16x8 bfv[4];
            #pragma unroll
            for (int nt = 0; nt < 4; ++nt)
                bfv[nt] = *(const bf16x8*)&Bb[buf][(((wn << 6) + (nt << 4) + lr) << 5) + (qd << 3)];
            #pragma unroll
            for (int nt = 0; nt < 4; ++nt)
                acc[nt] = __builtin_amdgcn_mfma_f32_16x16x32_bf16(afu.v, bfv[nt], acc[nt], 0, 0, 0);
            float tn;
            tn = fmaf(2.f * u0, tc0, -tp0); tp0 = tc0; tc0 = tn;
            tn = fmaf(2.f * u1, tc1, -tp1); tp1 = tc1; tc1 = tn;
            tn = fmaf(2.f * u2, tc2, -tp2); tp2 = tc2; tc2 = tn;
            tn = fmaf(2.f * u3, tc3, -tp3); tp3 = tc3; tc3 = tn;
            tn = fmaf(2.f * u4, tc4, -tp4); tp4 = tc4; tc4 = tn;
            tn = fmaf(2.f * u5, tc5, -tp5); tp5 = tc5; tc5 = tn;
            tn = fmaf(2.f * u6, tc6, -tp6); tp6 = tc6; tc6 = tn;
            tn = fmaf(2.f * u7, tc7, -tp7); tp7 = tc7; tc7 = tn;
        }
    }

    // epilogue: bias + depthwise conv3 (+ transposed bf16 K-copy for mix)
    #pragma unroll
    for (int nt = 0; nt < 4; ++nt) {
        const int col = (wn << 6) + (nt << 4) + lr;
        const float ww0 = w[col * 3 + 0], ww1 = w[col * 3 + 1], ww2 = w[col * 3 + 2];
        const float bs = bias[col];
        #pragma unroll
        for (int r = 0; r < 4; ++r) {
            const int row = (wm << 4) + (qd << 2) + r;
            const int gm = mb + row;
            const int n = gm & Lmask;
            const size_t gi = (size_t)gm * 128 + col;
            float xm1 = (n > 0)     ? x[gi - 128] : 0.f;
            float x0v = x[gi];
            float xp1 = (n < Lmask) ? x[gi + 128] : 0.f;
            float v = acc[nt][r] + bs + fmaf(ww0, xm1, fmaf(ww1, x0v, ww2 * xp1));
            outp[gi] = v;
            if (kt)
                kt[(size_t)((gm >> lgL) * 128 + col) * 448 + n] = f2bf(v);
        }
    }
}

// ---------------------------------------------------------------------------
extern "C" void kernel_launch(void* const* d_in, const int* in_sizes, int n_in,
                              void* d_out, int out_size, void* d_ws, size_t ws_size,
                              hipStream_t stream) {
    const float* x0 = (const float*)d_in[0];
    const float* x1 = (const float*)d_in[1];
    const float* x2 = (const float*)d_in[2];
    const float* x3 = (const float*)d_in[3];
    const float* c0 = (const float*)d_in[4];
    const float* w0 = (const float*)d_in[5];
    const float* c1 = (const float*)d_in[6];
    const float* w1 = (const float*)d_in[7];
    const float* c2 = (const float*)d_in[8];
    const float* w2 = (const float*)d_in[9];
    const float* c3 = (const float*)d_in[10];
    const float* w3 = (const float*)d_in[11];
    float* out = (float*)d_out;

    // ws layout — IDENTICAL total footprint to the proven R6 layout
    // (88,950,784 B). Wcat2/Wcat3 alias the Xt3 region (dead after up2_dec);
    // Ktall occupies exactly the space Xtm0..2 used to.
    float* d0 = (float*)d_ws;                               // 8388608 f
    float* d1 = d0 + 8388608;                               // 4194304 f
    float* d2 = d1 + 4194304;                               // 2097152 f
    unsigned short* Xt1   = (unsigned short*)(d2 + 2097152); // 4194304 us
    unsigned short* Xt2   = Xt1 + 4194304;                  // 2097152
    unsigned short* Xt3   = Xt2 + 2097152;                  // 1048576
    unsigned short* Wcat2 = Xt3;                            // 49152 (alias)
    unsigned short* Wcat3 = Wcat2 + 49152;                  // 229376 (alias)
    unsigned short* Ktall = Xt3 + 1048576;                  // 7340032
    unsigned short* BmT   = Ktall + 7340032;                // 262144
    float* bias_all = (float*)(BmT + 262144);               // 512 f
    unsigned short* U256 = (unsigned short*)(bias_all + 512);
    unsigned short* U128 = U256 + 131072;
    unsigned short* U64p = U128 + 32768;                    // 8192

    float* m3 = out;                                        // (128,512,128)
    float* m2 = m3 + 8388608;                               // (128,256,128)
    float* m1 = m2 + 4194304;                               // (128,128,128)
    float* m0 = m1 + 2097152;                               // (128, 64,128)

    prep_all<<<1824, 256, 0, stream>>>(x1, x2, x3, Xt1, Xt2, Xt3,
                                       U256, U128, U64p,
                                       c0, c1, c2, c3, BmT, bias_all);

    up2_dec<<<1792, 256, 0, stream>>>(U64p, U128, U256, Xt3, Xt2, Xt1,
                                      x2, x1, x0, d2, d1, d0);

    // compose AFTER up2_dec: Wcat aliases Xt3 (its last reader is up2_dec)
    compose1<<<960, 256, 0, stream>>>(U64p, U128, U256, Wcat2, Wcat3);
    compose2<<<128, 256, 0, stream>>>(U64p, Wcat3);

    mkan_all<<<3840, 256, 0, stream>>>(x3, d2, d1, d0, BmT, bias_all,
                                       w0, w1, w2, w3, m0, m1, m2, m3, Ktall);

    mix_fused<<<1792, 256, 0, stream>>>(U64p, Wcat2, Wcat3, Ktall, m1, m2, m3);
}

// Round 5
// 264.514 us; speedup vs baseline: 1.1944x; 1.1944x over previous
//
#include <hip/hip_runtime.h>
#include <math.h>

typedef __attribute__((ext_vector_type(8))) short bf16x8;
typedef __attribute__((ext_vector_type(4))) float f32x4;

__device__ __forceinline__ unsigned short f2bf(float f) {
    unsigned u = __float_as_uint(f);
    unsigned r = (u + 0x7FFF + ((u >> 16) & 1)) >> 16;   // RNE; inputs finite
    return (unsigned short)r;
}

// fast tanh: 1 - 2/(e^{2x}+1) via v_exp_f32 + v_rcp_f32 (validated R5/R6).
__device__ __forceinline__ float fast_tanh(float x) {
    float e2 = __builtin_amdgcn_exp2f(x * 2.885390081777927f);  // 2*log2(e)
    return fmaf(-2.0f, __builtin_amdgcn_rcpf(e2 + 1.0f), 1.0f);
}

// async global->LDS, 16B per lane; LDS dest = wave-uniform base + lane*16.
__device__ __forceinline__ void gload_lds16(const unsigned short* g,
                                            unsigned short* l) {
    __builtin_amdgcn_global_load_lds(
        (const __attribute__((address_space(1))) unsigned int*)g,
        (__attribute__((address_space(3))) unsigned int*)l, 16, 0, 0);
}

// ---------------------------------------------------------------------------
// castT_tile: one 64(n) x 128(c) tile of fp32 (B,L,128) -> bf16 (B,128,L).
// ---------------------------------------------------------------------------
__device__ __forceinline__ void castT_tile(
    const float* __restrict__ src, unsigned short* __restrict__ dst,
    int b, int n0, int L)
{
    __shared__ unsigned short tt[128][72];
    const int tid = threadIdx.x;
    for (int i = tid; i < 64 * 32; i += 256) {
        int nr = i >> 5, c4 = (i & 31) * 4;
        float4 v = *(const float4*)(src + ((size_t)b * L + n0 + nr) * 128 + c4);
        tt[c4 + 0][nr] = f2bf(v.x);
        tt[c4 + 1][nr] = f2bf(v.y);
        tt[c4 + 2][nr] = f2bf(v.z);
        tt[c4 + 3][nr] = f2bf(v.w);
    }
    __syncthreads();
    const int c = tid >> 1, seg = (tid & 1) * 32;
    unsigned short* dp = dst + ((size_t)b * 128 + c) * L + n0 + seg;
    #pragma unroll
    for (int j = 0; j < 32; j += 8)
        *(bf16x8*)(dp + j) = *(const bf16x8*)&tt[c][seg + j];
}

// ---------------------------------------------------------------------------
// prep_all: ONE dispatch for all independent prep work (R6-proven).
// ---------------------------------------------------------------------------
__global__ __launch_bounds__(256) void prep_all(
    const float* __restrict__ x1, const float* __restrict__ x2,
    const float* __restrict__ x3,
    unsigned short* __restrict__ Xt1, unsigned short* __restrict__ Xt2,
    unsigned short* __restrict__ Xt3,
    unsigned short* __restrict__ U256, unsigned short* __restrict__ U128,
    unsigned short* __restrict__ U64p,
    const float* __restrict__ c0, const float* __restrict__ c1,
    const float* __restrict__ c2, const float* __restrict__ c3,
    unsigned short* __restrict__ BmT_all, float* __restrict__ bias_all)
{
    const int bid = blockIdx.x, tid = threadIdx.x;
    if (bid < 896) {
        if (bid < 512)      castT_tile(x1, Xt1, bid >> 2, (bid & 3) * 64, 256);
        else if (bid < 768) castT_tile(x2, Xt2, (bid - 512) >> 1, ((bid - 512) & 1) * 64, 128);
        else                castT_tile(x3, Xt3, bid - 768, 0, 64);
    } else if (bid < 1568) {
        int fid = (bid - 896) * 256 + tid;
        unsigned short* U; int L, lg, e;
        if (fid < 131072)      { U = U256; L = 256; lg = 8; e = fid; }
        else if (fid < 163840) { U = U128; L = 128; lg = 7; e = fid - 131072; }
        else                   { U = U64p; L = 64;  lg = 6; e = fid - 163840; }
        const int n = e & (L - 1);
        const int m = e >> lg;
        const int t = m >> 1;
        const float inv4L = 1.0f / (4.0f * (float)L);
        float val;
        if ((m & 1) == 0) {
            val = ((t == n) ? 0.25f : 0.0f) + (((t + n) & 1) ? -inv4L : inv4L);
        } else {
            int idx = (t - n) & (L - 1);
            double th = M_PI * (2.0 * idx + 1.0) / (2.0 * L);
            double ct = cos(th) / sin(th);
            val = (float)((idx & 1) ? -ct : ct) * inv4L;
        }
        U[e] = f2bf(val);
    } else {
        const int r   = bid - 1568;          // 0..255
        const int set = r >> 6;              // 0..3  (DEG1 = set+2)
        const int o   = ((r & 63) << 1) + (tid >> 7);
        const int i   = tid & 127;
        const int DEG1 = set + 2;
        const float* cc = (set == 0) ? c0 : (set == 1) ? c1 : (set == 2) ? c2 : c3;
        const float* cp = cc + ((size_t)i * 128 + o) * DEG1;
        unsigned short* Bm = BmT_all + (size_t)set * 65536;
        for (int d = 1; d < DEG1; ++d)
            Bm[(size_t)(d - 1) * 16384 + o * 128 + i] = f2bf(cp[d]);
        float s = cp[0];
        #pragma unroll
        for (int off = 32; off >= 1; off >>= 1) s += __shfl_down(s, off);
        __shared__ float red[4];
        if ((tid & 63) == 0) red[tid >> 6] = s;
        __syncthreads();
        if ((tid & 127) == 0)
            bias_all[set * 128 + o] = red[tid >> 6] + red[(tid >> 6) + 1];
    }
}

// ---------------------------------------------------------------------------
// up2_body: out[b,m,c] = xh[b,m,c] + sign * sum_n U[m,n]*Xt[b,c,n]
// 64x128 tile, 4 waves 2x2 of 32x64, mfma 16x16x32 bf16, gload_lds staging
// (R6-proven). Optional bf16-transposed copy -> xtm feeds the next level.
// ---------------------------------------------------------------------------
__device__ __forceinline__ void up2_body(
    const unsigned short* __restrict__ U,
    const unsigned short* __restrict__ Xt,
    const float* __restrict__ xh,
    float* __restrict__ out,
    unsigned short* __restrict__ xtm,
    float sign, int b, int mt, int L)
{
    const int NK = L >> 5;
    const int tid = threadIdx.x;
    __shared__ unsigned short Ab[2][2048];
    __shared__ unsigned short Bb[2][4096];

    const int ln = tid & 63, wv = tid >> 6;
    const int wm = wv & 1, wn = wv >> 1;
    const int lr = ln & 15, qd = ln >> 4;

    f32x4 acc[2][4];
    #pragma unroll
    for (int mi = 0; mi < 2; ++mi)
        #pragma unroll
        for (int nt = 0; nt < 4; ++nt)
            acc[mi][nt] = (f32x4){0.f, 0.f, 0.f, 0.f};

    const int arow = tid >> 2, acol = (tid & 3) * 8;

    auto stage = [&](int kk, int buf) {
        const unsigned short* ga = U + (size_t)(mt * 64 + arow) * L + kk * 32 + acol;
        gload_lds16(ga, (unsigned short*)Ab[buf] + (tid << 3));
        #pragma unroll
        for (int j = 0; j < 2; ++j) {
            int sidx = tid + (j << 8);
            const unsigned short* gb =
                Xt + ((size_t)b * 128 + (sidx >> 2)) * L + kk * 32 + (sidx & 3) * 8;
            gload_lds16(gb, (unsigned short*)Bb[buf] + (sidx << 3));
        }
    };

    stage(0, 0);
    for (int kk = 0; kk < NK; ++kk) {
        __syncthreads();                     // drains async loads for buf kk
        if (kk + 1 < NK) stage(kk + 1, (kk + 1) & 1);
        const int buf = kk & 1;
        bf16x8 af[2], bfv[4];
        #pragma unroll
        for (int mi = 0; mi < 2; ++mi)
            af[mi] = *(const bf16x8*)&Ab[buf][(wm * 32 + mi * 16 + lr) * 32 + qd * 8];
        #pragma unroll
        for (int nt = 0; nt < 4; ++nt)
            bfv[nt] = *(const bf16x8*)&Bb[buf][(wn * 64 + nt * 16 + lr) * 32 + qd * 8];
        #pragma unroll
        for (int mi = 0; mi < 2; ++mi)
            #pragma unroll
            for (int nt = 0; nt < 4; ++nt)
                acc[mi][nt] = __builtin_amdgcn_mfma_f32_16x16x32_bf16(
                    af[mi], bfv[nt], acc[mi][nt], 0, 0, 0);
    }

    const int twoL = L << 1;
    #pragma unroll
    for (int nt = 0; nt < 4; ++nt) {
        const int col = wn * 64 + nt * 16 + lr;
        #pragma unroll
        for (int mi = 0; mi < 2; ++mi) {
            #pragma unroll
            for (int r = 0; r < 4; ++r) {
                const int row = mt * 64 + wm * 32 + mi * 16 + qd * 4 + r;
                const size_t gi = ((size_t)b * twoL + row) * 128 + col;
                float v = xh[gi] + sign * acc[mi][nt][r];
                out[gi] = v;
                if (xtm)
                    xtm[((size_t)b * 128 + col) * twoL + row] = f2bf(v);
            }
        }
    }
}

// up2_dec: all three decomposition GEMMs in ONE dispatch.
__global__ __launch_bounds__(256) void up2_dec(
    const unsigned short* __restrict__ U64p, const unsigned short* __restrict__ U128,
    const unsigned short* __restrict__ U256,
    const unsigned short* __restrict__ Xt3, const unsigned short* __restrict__ Xt2,
    const unsigned short* __restrict__ Xt1,
    const float* __restrict__ x2, const float* __restrict__ x1,
    const float* __restrict__ x0,
    float* __restrict__ d2, float* __restrict__ d1, float* __restrict__ d0)
{
    const int bid = blockIdx.x;
    const unsigned short *U, *Xt; const float* xh; float* out;
    int L, lgMT, base;
    if (bid < 256)      { U = U64p; Xt = Xt3; xh = x2; out = d2; L = 64;  lgMT = 1; base = 0; }
    else if (bid < 768) { U = U128; Xt = Xt2; xh = x1; out = d1; L = 128; lgMT = 2; base = 256; }
    else                { U = U256; Xt = Xt1; xh = x0; out = d0; L = 256; lgMT = 3; base = 768; }
    const int rb = bid - base;
    up2_body(U, Xt, xh, out, nullptr, -1.f, rb >> lgMT, rb & ((1 << lgMT) - 1), L);
}

// up2_mix: one mix-chain up-add (in-place), optional Xtm emit for next level.
__global__ __launch_bounds__(256) void up2_mix(
    const unsigned short* __restrict__ U, const unsigned short* __restrict__ Xt,
    float* __restrict__ m, unsigned short* __restrict__ xtm, int L, int lgMT)
{
    up2_body(U, Xt, m, m, xtm, 1.f,
             blockIdx.x >> lgMT, blockIdx.x & ((1 << lgMT) - 1), L);
}

// ---------------------------------------------------------------------------
// mkan_all: ALL FOUR mkan levels in one dispatch.
// R9 = R6 structure + R8's register-Chebyshev inner loop (validated):
// LDS holds only u = tanh(tanh(x)) fp32 (16.9KB padded); Chebyshev planes
// generated IN REGISTERS in a reordered K-loop (col-chunk outer, plane
// inner — MFMA accumulation order is free), A-fragments packed with
// v_cvt_pk_bf16_f32 (RNE == f2bf). LDS 48->33.3KB (3->4 blocks/CU).
// Epilogue = R6's light version: bias + dwconv + Xtm0 emit (level 0 only).
// ---------------------------------------------------------------------------
__global__ __launch_bounds__(256) void mkan_all(
    const float* __restrict__ xa, const float* __restrict__ xb,
    const float* __restrict__ xc, const float* __restrict__ xd,
    const unsigned short* __restrict__ BmT_all,
    const float* __restrict__ bias_all,
    const float* __restrict__ w0p, const float* __restrict__ w1p,
    const float* __restrict__ w2p, const float* __restrict__ w3p,
    float* __restrict__ m0, float* __restrict__ m1,
    float* __restrict__ m2, float* __restrict__ m3,
    unsigned short* __restrict__ xtm0)
{
    __shared__ float Us[32][132];            // +4 pad: bank-spread, 16B-aligned
    __shared__ unsigned short Bb[2][4096];

    const int bid = blockIdx.x, tid = threadIdx.x;
    const float *x, *w; float* outp; unsigned short* xtm = nullptr;
    int set, mb, Lmask;
    if (bid < 256)       { x = xa; w = w0p; outp = m0; set = 0; mb = bid << 5;          Lmask = 63;  xtm = xtm0; }
    else if (bid < 768)  { x = xb; w = w1p; outp = m1; set = 1; mb = (bid - 256) << 5;  Lmask = 127; }
    else if (bid < 1792) { x = xc; w = w2p; outp = m2; set = 2; mb = (bid - 768) << 5;  Lmask = 255; }
    else                 { x = xd; w = w3p; outp = m3; set = 3; mb = (bid - 1792) << 5; Lmask = 511; }
    const int deg1m1 = set + 1;
    const int NK = deg1m1 << 2;
    const unsigned short* Bm = BmT_all + (size_t)set * 65536;
    const float* bias = bias_all + (set << 7);

    auto stageB = [&](int p, int c4, int buf) {
        const int i0 = c4 << 5;
        #pragma unroll
        for (int j = 0; j < 2; ++j) {
            int sidx = tid + (j << 8);
            const unsigned short* gb =
                Bm + (size_t)((p << 7) + (sidx >> 2)) * 128 + i0 + ((sidx & 3) << 3);
            gload_lds16(gb, (unsigned short*)Bb[buf] + (sidx << 3));
        }
    };

    stageB(0, 0, 0);                         // flies during tanh prep

    // ---- prep: u = tanh(tanh(x)) fp32 into Us ----
    for (int e = tid * 4; e < 4096; e += 1024) {
        const int row = e >> 7, i = e & 127;
        float4 v = *(const float4*)(x + ((size_t)(mb + row)) * 128 + i);
        float4 r;
        r.x = fast_tanh(fast_tanh(v.x));
        r.y = fast_tanh(fast_tanh(v.y));
        r.z = fast_tanh(fast_tanh(v.z));
        r.w = fast_tanh(fast_tanh(v.w));
        *(float4*)&Us[row][i] = r;
    }

    const int ln = tid & 63, wv = tid >> 6;
    const int wm = wv & 1, wn = wv >> 1;
    const int lr = ln & 15, qd = ln >> 4;
    const int arow = (wm << 4) + lr;

    f32x4 acc[4];
    #pragma unroll
    for (int nt = 0; nt < 4; ++nt) acc[nt] = (f32x4){0.f, 0.f, 0.f, 0.f};

    __syncthreads();                         // Us ready + stage(0) drained

    int s = 0;
    for (int c4 = 0; c4 < 4; ++c4) {
        const float4 ua = *(const float4*)&Us[arow][(c4 << 5) + (qd << 3)];
        const float4 ub = *(const float4*)&Us[arow][(c4 << 5) + (qd << 3) + 4];
        const float u0 = ua.x, u1 = ua.y, u2 = ua.z, u3 = ua.w;
        const float u4 = ub.x, u5 = ub.y, u6 = ub.z, u7 = ub.w;
        float tp0 = 1.f, tp1 = 1.f, tp2 = 1.f, tp3 = 1.f;
        float tp4 = 1.f, tp5 = 1.f, tp6 = 1.f, tp7 = 1.f;
        float tc0 = u0, tc1 = u1, tc2 = u2, tc3 = u3;
        float tc4 = u4, tc5 = u5, tc6 = u6, tc7 = u7;
        for (int p = 0; p < deg1m1; ++p, ++s) {
            if (s) __syncthreads();
            if (s + 1 < NK) {
                int np = p + 1, nc4 = c4;
                if (np == deg1m1) { np = 0; ++nc4; }
                stageB(np, nc4, (s + 1) & 1);
            }
            union { unsigned int w[4]; bf16x8 v; } afu;
            asm("v_cvt_pk_bf16_f32 %0, %1, %2" : "=v"(afu.w[0]) : "v"(tc0), "v"(tc1));
            asm("v_cvt_pk_bf16_f32 %0, %1, %2" : "=v"(afu.w[1]) : "v"(tc2), "v"(tc3));
            asm("v_cvt_pk_bf16_f32 %0, %1, %2" : "=v"(afu.w[2]) : "v"(tc4), "v"(tc5));
            asm("v_cvt_pk_bf16_f32 %0, %1, %2" : "=v"(afu.w[3]) : "v"(tc6), "v"(tc7));
            const int buf = s & 1;
            bf16x8 bfv[4];
            #pragma unroll
            for (int nt = 0; nt < 4; ++nt)
                bfv[nt] = *(const bf16x8*)&Bb[buf][(((wn << 6) + (nt << 4) + lr) << 5) + (qd << 3)];
            #pragma unroll
            for (int nt = 0; nt < 4; ++nt)
                acc[nt] = __builtin_amdgcn_mfma_f32_16x16x32_bf16(afu.v, bfv[nt], acc[nt], 0, 0, 0);
            float tn;
            tn = fmaf(2.f * u0, tc0, -tp0); tp0 = tc0; tc0 = tn;
            tn = fmaf(2.f * u1, tc1, -tp1); tp1 = tc1; tc1 = tn;
            tn = fmaf(2.f * u2, tc2, -tp2); tp2 = tc2; tc2 = tn;
            tn = fmaf(2.f * u3, tc3, -tp3); tp3 = tc3; tc3 = tn;
            tn = fmaf(2.f * u4, tc4, -tp4); tp4 = tc4; tc4 = tn;
            tn = fmaf(2.f * u5, tc5, -tp5); tp5 = tc5; tc5 = tn;
            tn = fmaf(2.f * u6, tc6, -tp6); tp6 = tc6; tc6 = tn;
            tn = fmaf(2.f * u7, tc7, -tp7); tp7 = tc7; tc7 = tn;
        }
    }

    // epilogue: bias + depthwise conv3 (+ bf16-T copy for level 0 only)
    #pragma unroll
    for (int nt = 0; nt < 4; ++nt) {
        const int col = (wn << 6) + (nt << 4) + lr;
        const float ww0 = w[col * 3 + 0], ww1 = w[col * 3 + 1], ww2 = w[col * 3 + 2];
        const float bs = bias[col];
        #pragma unroll
        for (int r = 0; r < 4; ++r) {
            const int row = (wm << 4) + (qd << 2) + r;
            const int gm = mb + row;
            const int n = gm & Lmask;
            const size_t gi = (size_t)gm * 128 + col;
            float xm1 = (n > 0)     ? x[gi - 128] : 0.f;
            float x0v = x[gi];
            float xp1 = (n < Lmask) ? x[gi + 128] : 0.f;
            float v = acc[nt][r] + bs + fmaf(ww0, xm1, fmaf(ww1, x0v, ww2 * xp1));
            outp[gi] = v;
            if (xtm)
                xtm[(size_t)(((gm >> 6) << 7) + col) * 64 + (gm & 63)] = f2bf(v);
        }
    }
}

// ---------------------------------------------------------------------------
extern "C" void kernel_launch(void* const* d_in, const int* in_sizes, int n_in,
                              void* d_out, int out_size, void* d_ws, size_t ws_size,
                              hipStream_t stream) {
    const float* x0 = (const float*)d_in[0];
    const float* x1 = (const float*)d_in[1];
    const float* x2 = (const float*)d_in[2];
    const float* x3 = (const float*)d_in[3];
    const float* c0 = (const float*)d_in[4];
    const float* w0 = (const float*)d_in[5];
    const float* c1 = (const float*)d_in[6];
    const float* w1 = (const float*)d_in[7];
    const float* c2 = (const float*)d_in[8];
    const float* w2 = (const float*)d_in[9];
    const float* c3 = (const float*)d_in[10];
    const float* w3 = (const float*)d_in[11];
    float* out = (float*)d_out;

    // ws: d0|d1|d2 (56MB) + Xt1..3 + Xtm0..2 (29MB) + BmT + bias + U (~0.9MB)
    // (identical proven R6 layout, 88.95MB)
    float* d0 = (float*)d_ws;                               // 8388608 f
    float* d1 = d0 + 8388608;                               // 4194304 f
    float* d2 = d1 + 4194304;                               // 2097152 f
    unsigned short* Xt1  = (unsigned short*)(d2 + 2097152); // 4194304 us
    unsigned short* Xt2  = Xt1 + 4194304;                   // 2097152
    unsigned short* Xt3  = Xt2 + 2097152;                   // 1048576
    unsigned short* Xtm0 = Xt3 + 1048576;                   // 1048576
    unsigned short* Xtm1 = Xtm0 + 1048576;                  // 2097152
    unsigned short* Xtm2 = Xtm1 + 2097152;                  // 4194304
    unsigned short* BmT  = Xtm2 + 4194304;                  // 262144
    float* bias_all = (float*)(BmT + 262144);               // 512 f
    unsigned short* U256 = (unsigned short*)(bias_all + 512);
    unsigned short* U128 = U256 + 131072;
    unsigned short* U64p = U128 + 32768;                    // 8192

    float* m3 = out;                                        // (128,512,128)
    float* m2 = m3 + 8388608;                               // (128,256,128)
    float* m1 = m2 + 4194304;                               // (128,128,128)
    float* m0 = m1 + 2097152;                               // (128, 64,128)

    // 6 dispatches (R6-proven sequence)
    prep_all<<<1824, 256, 0, stream>>>(x1, x2, x3, Xt1, Xt2, Xt3,
                                       U256, U128, U64p,
                                       c0, c1, c2, c3, BmT, bias_all);

    up2_dec<<<1792, 256, 0, stream>>>(U64p, U128, U256, Xt3, Xt2, Xt1,
                                      x2, x1, x0, d2, d1, d0);

    mkan_all<<<3840, 256, 0, stream>>>(x3, d2, d1, d0, BmT, bias_all,
                                       w0, w1, w2, w3, m0, m1, m2, m3, Xtm0);

    up2_mix<<<256,  256, 0, stream>>>(U64p, Xtm0, m1, Xtm1, 64, 1);
    up2_mix<<<512,  256, 0, stream>>>(U128, Xtm1, m2, Xtm2, 128, 2);
    up2_mix<<<1024, 256, 0, stream>>>(U256, Xtm2, m3, nullptr, 256, 3);
}